// Round 6
// baseline (10874.334 us; speedup 1.0000x reference)
//
#include <hip/hip_runtime.h>
#include <cstdint>
#include <cstddef>

// B=256, P=196, C=512, D=512, A=256, E=256, V=193, TC=256, T=255

typedef unsigned short u16;
typedef unsigned int u32;
typedef unsigned long long ull;
typedef __attribute__((ext_vector_type(8))) short short8;
typedef __attribute__((ext_vector_type(4))) float f32x4;

__device__ __forceinline__ float sigf(float x){ return 1.f/(1.f+expf(-x)); }
__device__ __forceinline__ u16 f2bf(float f){
  u32 u = __builtin_bit_cast(u32, f);
  u32 r = (u + 0x7fffu + ((u>>16)&1u)) >> 16;
  return (u16)r;
}
__device__ __forceinline__ float bf2f(u16 u){
  u32 x = ((u32)u) << 16;
  return __builtin_bit_cast(float, x);
}

// ---- coherent (LLC-level) relaxed access: no cache writeback/invalidate, ever ----
__device__ __forceinline__ void st_dev_f32(float* p, float v){
  __hip_atomic_store(p, v, __ATOMIC_RELAXED, __HIP_MEMORY_SCOPE_AGENT);
}
__device__ __forceinline__ float ld_dev_f32(const float* p){
  return __hip_atomic_load(p, __ATOMIC_RELAXED, __HIP_MEMORY_SCOPE_AGENT);
}
__device__ __forceinline__ void st_dev_u16(u16* p, u16 v){
  __hip_atomic_store(p, v, __ATOMIC_RELAXED, __HIP_MEMORY_SCOPE_AGENT);
}
__device__ __forceinline__ void st_dev_u32(u32* p, u32 v){
  __hip_atomic_store(p, v, __ATOMIC_RELAXED, __HIP_MEMORY_SCOPE_AGENT);
}
__device__ __forceinline__ u32 ld_dev_u32(const u32* p){
  return __hip_atomic_load(p, __ATOMIC_RELAXED, __HIP_MEMORY_SCOPE_AGENT);
}

__device__ __forceinline__ void wait_vm1(int ahead){
  switch(ahead){
    case 5: asm volatile("s_waitcnt vmcnt(5)" ::: "memory"); break;
    case 4: asm volatile("s_waitcnt vmcnt(4)" ::: "memory"); break;
    case 3: asm volatile("s_waitcnt vmcnt(3)" ::: "memory"); break;
    case 2: asm volatile("s_waitcnt vmcnt(2)" ::: "memory"); break;
    case 1: asm volatile("s_waitcnt vmcnt(1)" ::: "memory"); break;
    default: asm volatile("s_waitcnt vmcnt(0)" ::: "memory"); break;
  }
}

// ---- flag-based sync: producers STORE (no RMW) to their own slot; consumers
// poll wave-parallel. __syncthreads (vmcnt-drain) before the flag store orders
// the block's data stores ahead of the signal at the coherent point. ----
__device__ __forceinline__ void flag_store(int* f, int v){
  __syncthreads();
  if (threadIdx.x == 0)
    __hip_atomic_store(f, v, __ATOMIC_RELAXED, __HIP_MEMORY_SCOPE_AGENT);
}
// wave 0 polls n (<=64) flags; returns when all >= target. Ends in syncthreads.
__device__ __forceinline__ void flags_wait(const int* f, int n, int target){
  if (threadIdx.x < 64){
    const int lane = threadIdx.x;
    int spins = 0;
    for (;;){
      int v = (lane < n) ? __hip_atomic_load(&f[lane], __ATOMIC_RELAXED, __HIP_MEMORY_SCOPE_AGENT)
                         : 0x7fffffff;
      if (__all(v >= target)) break;
      if (++spins > (1<<20)) break;   // bailout: wrong results, never a hang
      __builtin_amdgcn_s_sleep(1);
    }
  }
  __syncthreads();
}

// ---------------- zero preds/alphas + sync flags ----------------
__global__ void k_zero(float* a, int na4, float* b, int nb4, int* ctr){
  int i = blockIdx.x*blockDim.x + threadIdx.x;
  int stride = gridDim.x*blockDim.x;
  float4 z = make_float4(0.f,0.f,0.f,0.f);
  for (int j = i; j < na4; j += stride) ((float4*)a)[j] = z;
  for (int j = i; j < nb4; j += stride) ((float4*)b)[j] = z;
  if (i < 512) ctr[i] = 0;
}

// ---------------- sort (stable descending by length) ----------------
__global__ void k_sort(const int* cap_lens, int* si, int* dlw, float* out_dl, float* out_si){
  __shared__ int lens[256];
  int tid = threadIdx.x;
  lens[tid] = cap_lens[tid];
  __syncthreads();
  int L = lens[tid];
  int rank = 0;
  for (int j = 0; j < 256; ++j){
    int Lj = lens[j];
    rank += ((Lj > L) || (Lj == L && j < tid)) ? 1 : 0;
  }
  si[rank] = tid;
  dlw[rank] = L - 1;
  out_dl[rank] = (float)(L - 1);
  out_si[rank] = (float)tid;
}

// ---------------- caps gather ----------------
__global__ void k_caps(const int* caps, const int* si, int* caps_s, float* out_caps){
  int b = blockIdx.x, t = threadIdx.x;
  int v = caps[si[b]*256 + t];
  caps_s[b*256 + t] = v;
  out_caps[b*256 + t] = (float)v;
}

// ---------------- gather+convert encoder rows to bf16 (sorted order) ----------------
__global__ void k_prep(const float* enc, const int* si, u16* enc_sb){
  int b = blockIdx.x, tid = threadIdx.x;
  const float* src = enc + (size_t)si[b]*100352;   // 196*512
  u16* dst = enc_sb + (size_t)b*100352;
  for (int i = tid; i < 25088; i += 256){
    float4 v = *(const float4*)&src[i*4];
    ushort4 o;
    o.x = f2bf(v.x); o.y = f2bf(v.y); o.z = f2bf(v.z); o.w = f2bf(v.w);
    *(ushort4*)&dst[i*4] = o;
  }
}

// ---------------- mean of encoder rows (sorted order), bf16 out ----------------
__global__ void k_mean(const float* enc, const int* si, u16* mean_bf){
  int b = blockIdx.x, tid = threadIdx.x;
  const float* eb = enc + (size_t)si[b]*100352;
  int cc = 2*tid;
  float s0 = 0.f, s1 = 0.f;
  #pragma unroll 4
  for (int pp = 0; pp < 196; ++pp){
    float2 v = *(const float2*)&eb[(size_t)pp*512 + cc];
    s0 += v.x; s1 += v.y;
  }
  mean_bf[b*512 + cc]     = f2bf(s0 * (1.f/196.f));
  mean_bf[b*512 + cc + 1] = f2bf(s1 * (1.f/196.f));
}

// ---------------- weight concat + bf16 convert ----------------
struct ConcatP {
  const float *Wdec,*bdec,*Wfb,*bfb,*Wfc,*bfc,*Wih,*bih,*Whh,*bhh,*Winh,*binh,*Winc,*binc,*Wenc,*emb;
  u16 *Wc0,*Wc1,*Wc3,*Wenc_bf,*emb_bf;
  float *bc0,*bc1,*bc3;
};
__global__ void k_concat(ConcatP p){
  int idx = blockIdx.x*blockDim.x + threadIdx.x;
  int stride = gridDim.x*blockDim.x;
  for (int i = idx; i < 1024*512; i += stride){
    int n = i >> 9, k = i & 511;
    float v = (n < 512) ? p.Winh[n*512 + k] : p.Winc[(n-512)*512 + k];
    p.Wc0[i] = f2bf(v);
  }
  for (int i = idx; i < 1024; i += stride)
    p.bc0[i] = (i < 512) ? p.binh[i] : p.binc[i-512];
  for (int i = idx; i < 1024*512; i += stride){
    int n = i >> 9, k = i & 511;
    float v = (n < 256) ? p.Wdec[n*512+k]
            : (n < 768) ? p.Wfb[(n-256)*512+k]
            : (n < 961) ? p.Wfc[(n-768)*512+k] : 0.f;
    p.Wc1[i] = f2bf(v);
  }
  for (int i = idx; i < 1024; i += stride)
    p.bc1[i] = (i < 256) ? p.bdec[i] : (i < 768) ? p.bfb[i-256] : (i < 961) ? p.bfc[i-768] : 0.f;
  // Wc3: gate-interleaved [W_ih | W_hh] (2048 x 1280), row n'=4*j+g -> orig row g*512+j
  for (int i = idx; i < 2048*1280; i += stride){
    int n = i / 1280, k = i - n*1280;
    int j = n >> 2, g = n & 3, orow = g*512 + j;
    float v = (k < 768) ? p.Wih[orow*768 + k] : p.Whh[orow*512 + (k - 768)];
    p.Wc3[i] = f2bf(v);
  }
  for (int i = idx; i < 2048; i += stride){
    int j = i >> 2, g = i & 3, orow = g*512 + j;
    p.bc3[i] = p.bih[orow] + p.bhh[orow];
  }
  for (int i = idx; i < 256*512; i += stride) p.Wenc_bf[i] = f2bf(p.Wenc[i]);
  for (int i = idx; i < 193*256; i += stride) p.emb_bf[i] = f2bf(p.emb[i]);
}

// ---------------- bf16 MFMA GEMM (register-staged, 4 waves) — prologue only ----------------
// MODE 0: enc_att -> bf16 (+bias);  MODE 1: init h/c
struct MfmaP {
  const u16* A; const u16* Bw; const float* bias;
  int K, N;
  u16* out_bf;
  u16* h_bf; float* c;
};

template<int MODE, int NT>
__global__ __launch_bounds__(256) void k_mfma(MfmaP p){
  __shared__ __align__(16) unsigned char smem[16384 + 16384*NT];
  u16* As0 = (u16*)smem;                 // [2][64*64]
  u16* Bs0 = (u16*)(smem + 16384);       // [2][64*64*NT]

  const int tid  = threadIdx.x;
  const int bn0  = blockIdx.x * 64 * NT;
  const int bm0  = blockIdx.y * 64;
  const int wave = tid >> 6;
  const int lane = tid & 63;
  const int ln   = lane & 15;
  const int quad = lane >> 4;

  f32x4 acc[4][NT] = {};
  short8 pa[2], pb[2*NT];

  const int srow = tid >> 3;          // 0..31
  const int sgc  = tid & 7;           // granule col 0..7

  #pragma unroll
  for (int r = 0; r < 2; ++r)
    pa[r] = *(const short8*)(p.A + (size_t)(bm0 + srow + 32*r)*p.K + sgc*8);
  #pragma unroll
  for (int r = 0; r < 2*NT; ++r)
    pb[r] = *(const short8*)(p.Bw + (size_t)(bn0 + srow + 32*r)*p.K + sgc*8);
  #pragma unroll
  for (int r = 0; r < 2; ++r){
    int row = srow + 32*r;
    *(short8*)&As0[row*64 + ((sgc ^ (row & 7))<<3)] = pa[r];
  }
  #pragma unroll
  for (int r = 0; r < 2*NT; ++r){
    int row = srow + 32*r;
    *(short8*)&Bs0[row*64 + ((sgc ^ (row & 7))<<3)] = pb[r];
  }

  const int nIter = p.K >> 6;
  int ib = 0;
  for (int it = 0; ; ){
    __syncthreads();
    const bool more = (it + 1 < nIter);
    if (more){
      int k0 = (it + 1) << 6;
      #pragma unroll
      for (int r = 0; r < 2; ++r)
        pa[r] = *(const short8*)(p.A + (size_t)(bm0 + srow + 32*r)*p.K + k0 + sgc*8);
      #pragma unroll
      for (int r = 0; r < 2*NT; ++r)
        pb[r] = *(const short8*)(p.Bw + (size_t)(bn0 + srow + 32*r)*p.K + k0 + sgc*8);
    }
    const u16* As = &As0[ib*4096];
    const u16* Bs = &Bs0[ib*4096*NT];
    #pragma unroll
    for (int kk = 0; kk < 2; ++kk){
      short8 af[4], bfr[NT];
      #pragma unroll
      for (int mt = 0; mt < 4; ++mt){
        int row = mt*16 + ln;
        int g = kk*4 + quad;
        af[mt] = *(const short8*)&As[row*64 + ((g ^ (row & 7))<<3)];
      }
      #pragma unroll
      for (int nt = 0; nt < NT; ++nt){
        int row = (wave*NT + nt)*16 + ln;
        int g = kk*4 + quad;
        bfr[nt] = *(const short8*)&Bs[row*64 + ((g ^ (row & 7))<<3)];
      }
      #pragma unroll
      for (int mt = 0; mt < 4; ++mt)
        #pragma unroll
        for (int nt = 0; nt < NT; ++nt)
          acc[mt][nt] = __builtin_amdgcn_mfma_f32_16x16x32_bf16(af[mt], bfr[nt], acc[mt][nt], 0, 0, 0);
    }
    if (!more) break;
    ib ^= 1;
    u16* Aw = &As0[ib*4096];
    u16* Bww = &Bs0[ib*4096*NT];
    #pragma unroll
    for (int r = 0; r < 2; ++r){
      int row = srow + 32*r;
      *(short8*)&Aw[row*64 + ((sgc ^ (row & 7))<<3)] = pa[r];
    }
    #pragma unroll
    for (int r = 0; r < 2*NT; ++r){
      int row = srow + 32*r;
      *(short8*)&Bww[row*64 + ((sgc ^ (row & 7))<<3)] = pb[r];
    }
    ++it;
  }

  #pragma unroll
  for (int nt = 0; nt < NT; ++nt){
    int n = bn0 + (wave*NT + nt)*16 + ln;
    float bv = p.bias[n];
    #pragma unroll
    for (int mt = 0; mt < 4; ++mt)
      #pragma unroll
      for (int r = 0; r < 4; ++r){
        int m = bm0 + mt*16 + quad*4 + r;
        float v = acc[mt][nt][r] + bv;
        if (MODE == 0){
          p.out_bf[(size_t)m*p.N + n] = f2bf(v);
        } else { // MODE 1
          if (n < 512) p.h_bf[m*512 + n] = f2bf(v);
        else         p.c[m*512 + n - 512] = v;
        }
      }
  }
}

// ---------------- persistent kernel: whole t-loop ----------------
struct PersistP {
  const u16* Wc1; const float* bc1;
  const u16* Wc3; const float* bc3;
  u16* h_bf; float* c; u16* z_bf;
  float* dec_att; float* gatev; float* preds; float* alphas;
  const u16* enc_att; const u16* enc_sb;
  const float* wfull; const float* bfull;
  const u16* emb_bf; const int* caps_s;
  const int* dl;
  int* ctr;   // f1[4][16] at +0, f2[256] at +64, f3[4][32] at +320
};

// asm-staged ring GEMM over 64x64 tile, 16 waves, K-chunks of 64.
// A (h/z, cross-block) via sc1 coherent loads; B (weights) cached. Depth-6
// register ring, 4 LDS slots, counted vmcnt, ONE raw s_barrier per chunk.
template<int NC, int MODE>
__device__ void gemm_phase(const PersistP& p, unsigned char* smem, int bm0, int bn0, int t){
  constexpr int K = NC * 64;
  constexpr int DP = (NC < 6) ? NC : 6;
  const u16* A    = (MODE == 2) ? p.h_bf : p.z_bf;
  const u16* Bw   = (MODE == 2) ? p.Wc1  : p.Wc3;
  const float* bias = (MODE == 2) ? p.bc1 : p.bc3;

  const int tid = threadIdx.x;
  const int w = tid >> 6, l = tid & 63;
  const int half = tid >> 9;              // 0: stage A, 1: stage B (wave-uniform)
  const int loc = tid & 511;
  const int r = loc >> 3, g = loc & 7;    // row 0..63, granule 0..7
  u16* lds0 = (u16*)smem;                 // 4 slots x (A 4096 u16 + B 4096 u16)
  u16* ldst = lds0 + (half ? 4096 : 0) + r*64 + ((g ^ (r & 7)) << 3);
  const u16* gp = half ? (Bw + (size_t)(bn0 + r)*K + g*8)
                       : (A  + (size_t)(bm0 + r)*K + g*8);
  const int mt = w >> 2, nt = w & 3;
  const int ln = l & 15, quad = l >> 4;
  f32x4 acc = {0.f,0.f,0.f,0.f};

  f32x4 buf[6];
  auto issue = [&](int ci, int slot){
    const void* q = gp + ci*64;
    if (half == 0)
      asm volatile("global_load_dwordx4 %0, %1, off sc1" : "=&v"(buf[slot]) : "v"(q));
    else
      asm volatile("global_load_dwordx4 %0, %1, off"     : "=&v"(buf[slot]) : "v"(q));
  };
  auto wr = [&](int ci, int slot){
    *(f32x4*)(ldst + (ci & 3)*8192) = buf[slot];
  };
  auto compute = [&](int ci){
    const u16* As = lds0 + (ci & 3)*8192;
    const u16* Bs = As + 4096;
    #pragma unroll
    for (int kk = 0; kk < 2; ++kk){
      int gg = kk*4 + quad;
      int ra = mt*16 + ln;
      short8 af = *(const short8*)&As[ra*64 + ((gg ^ (ra & 7))<<3)];
      int rb = nt*16 + ln;
      short8 bv = *(const short8*)&Bs[rb*64 + ((gg ^ (rb & 7))<<3)];
      acc = __builtin_amdgcn_mfma_f32_16x16x32_bf16(af, bv, acc, 0, 0, 0);
    }
  };

  asm volatile("s_waitcnt vmcnt(0)" ::: "memory");
  #pragma unroll
  for (int s = 0; s < DP; ++s) issue(s, s);
  #pragma unroll
  for (int ci = 0; ci < NC; ++ci){
    wait_vm1(((ci + DP < NC) ? DP : (NC - ci)) - 1);
    __builtin_amdgcn_sched_barrier(0);
    wr(ci, ci % DP);
    asm volatile("s_waitcnt lgkmcnt(0)" ::: "memory");
    __builtin_amdgcn_s_barrier();
    __builtin_amdgcn_sched_barrier(0);
    if (ci + DP < NC) issue(ci + DP, ci % DP);
    compute(ci);
  }
  // drain own LDS reads, then block-wide barrier so smem can be reused
  asm volatile("s_waitcnt lgkmcnt(0)" ::: "memory");
  __builtin_amdgcn_s_barrier();

  if (MODE == 2){
    const int n = bn0 + nt*16 + ln;
    const float bv = bias[n];
    #pragma unroll
    for (int rr = 0; rr < 4; ++rr){
      int m = bm0 + mt*16 + quad*4 + rr;
      float v = acc[rr] + bv;
      if (n < 256)      st_dev_f32(&p.dec_att[m*256 + n], v);
      else if (n < 768) st_dev_f32(&p.gatev[m*512 + n - 256], sigf(v));
      else if (n < 961){
        int tp = t - 1;
        if (tp >= 0)
          p.preds[((size_t)m*255 + tp)*193 + (n - 768)] = (tp < p.dl[m]) ? v : 0.f;
      }
    }
  } else {
    // MODE 3: regroup gates via LDS, fused LSTM pointwise
    float* Cs = (float*)smem;           // 64 x 68 f32 overlay
    const int n_loc = nt*16 + ln;
    const float bv = bias[bn0 + n_loc];
    #pragma unroll
    for (int rr = 0; rr < 4; ++rr)
      Cs[(mt*16 + quad*4 + rr)*68 + n_loc] = acc[rr] + bv;
    __syncthreads();
    {
      int m = tid >> 4, jl = tid & 15;   // 64 rows x 16 quads = 1024
      float4 g4 = *(const float4*)&Cs[m*68 + jl*4];
      int gm = bm0 + m;
      int gj = (bn0 >> 2) + jl;
      if (t < p.dl[gm]){
        float ig = sigf(g4.x), fg = sigf(g4.y);
        float gg = tanhf(g4.z), og = sigf(g4.w);
        float cn = fg * p.c[gm*512 + gj] + ig * gg;   // c is block-private: cached
        float hn = og * tanhf(cn);
        p.c[gm*512 + gj] = cn;
        st_dev_u16(&p.h_bf[gm*512 + gj], f2bf(hn));
      }
    }
  }
}

// attention body for 1024 threads; gatev wait deferred to just before z-assembly.
__device__ void attn_phase(const PersistP& p, unsigned char* smem_raw, int b, int t,
                           const int* f_gate, int target){
  float* da  = (float*)smem_raw;        // 256
  float* wfs = da + 256;                // 256
  float* sc  = wfs + 256;               // 256
  float* awe = sc + 256;                // 4 x 512
  float* red = awe + 2048;              // 32
  const int tid = threadIdx.x;
  if (tid < 256){
    da[tid]  = ld_dev_f32(&p.dec_att[b*256 + tid]);
    wfs[tid] = p.wfull[tid];
  }
  __syncthreads();

  // scores: thread (pr, aq) partial over 64 A-entries
  {
    const int pr = tid >> 2, aq = tid & 3;
    float s = 0.f;
    if (pr < 196){
      const u16* row = p.enc_att + ((size_t)b*196 + pr)*256 + aq*64;
      const float* dd = &da[aq*64];
      const float* ww = &wfs[aq*64];
      #pragma unroll
      for (int i = 0; i < 8; ++i){
        short8 v = *(const short8*)(row + i*8);
        #pragma unroll
        for (int j = 0; j < 8; ++j)
          s += fmaxf(bf2f((u16)v[j]) + dd[i*8+j], 0.f) * ww[i*8+j];
      }
    }
    s += __shfl_xor(s, 1, 64);
    s += __shfl_xor(s, 2, 64);
    if ((tid & 3) == 0 && pr < 196) sc[pr] = s + p.bfull[0];
  }
  __syncthreads();

  const int wid = tid >> 6, lane = tid & 63;
  float sv = (tid < 196) ? sc[tid] : -1e30f;
  float mx = sv;
  for (int o = 32; o > 0; o >>= 1) mx = fmaxf(mx, __shfl_down(mx, o, 64));
  if (lane == 0) red[wid] = mx;
  __syncthreads();
  if (tid == 0) red[16] = fmaxf(fmaxf(red[0], red[1]), fmaxf(red[2], red[3]));
  __syncthreads();
  mx = red[16];
  float e = (tid < 196) ? expf(sv - mx) : 0.f;
  float sm = e;
  for (int o = 32; o > 0; o >>= 1) sm += __shfl_down(sm, o, 64);
  if (lane == 0) red[wid] = sm;
  __syncthreads();
  if (tid == 0) red[16] = red[0] + red[1] + red[2] + red[3];
  __syncthreads();
  const float inv = 1.f / red[16];
  if (tid < 256) sc[tid] = e * inv;
  __syncthreads();
  if (tid < 196)
    p.alphas[((size_t)b*255 + t)*196 + tid] = sc[tid];

  // awe: thread (q, cp)
  {
    const int q = tid >> 8, cp = tid & 255, cc = 2*cp;
    const u16* eb = p.enc_sb + (size_t)b*100352;
    const int p0 = q*49;
    float v0 = 0.f, v1 = 0.f;
    #pragma unroll 7
    for (int i = 0; i < 49; ++i){
      int pp = p0 + i;
      u32 u = *(const u32*)&eb[(size_t)pp*512 + cc];
      float a = sc[pp];
      v0 += a * bf2f((u16)(u & 0xffffu));
      v1 += a * bf2f((u16)(u >> 16));
    }
    *(float2*)&awe[q*512 + cc] = make_float2(v0, v1);
  }

  // gatev tiles ready? (also serves as the pre-combine __syncthreads)
  flags_wait(f_gate, 8, target);

  if (tid < 256){
    const int cc = 2*tid;
    float v0 = awe[0*512+cc]   + awe[1*512+cc]   + awe[2*512+cc]   + awe[3*512+cc];
    float v1 = awe[0*512+cc+1] + awe[1*512+cc+1] + awe[2*512+cc+1] + awe[3*512+cc+1];
    u16* zb = p.z_bf + (size_t)b*1280;
    float g0 = ld_dev_f32(&p.gatev[b*512 + cc]);
    float g1 = ld_dev_f32(&p.gatev[b*512 + cc + 1]);
    st_dev_u16(&zb[256 + cc],     f2bf(g0 * v0));
    st_dev_u16(&zb[256 + cc + 1], f2bf(g1 * v1));
    int tok = p.caps_s[b*256 + t];
    st_dev_u16(&zb[tid], p.emb_bf[tok*256 + tid]);
    st_dev_u32((u32*)&zb[768 + cc], ld_dev_u32((const u32*)&p.h_bf[b*512 + cc]));
  }
}

__global__ __launch_bounds__(1024) void k_persist(PersistP p){
  extern __shared__ __align__(16) unsigned char smem[];   // 96 KB dynamic -> 1 block/CU
  const int b = blockIdx.x;
  int* f1 = p.ctr;          // [4][16] K1 tile flags
  int* f2 = p.ctr + 64;     // [256]   attn flags
  int* f3 = p.ctr + 320;    // [4][32] K3 tile flags
  for (int t = 0; t <= 255; ++t){
    // phase 1: K1 GEMM on blocks 192..255 (16 x-tiles x 4 y-groups)
    if (b >= 192){
      const int idx = b - 192, x = idx & 15, y = idx >> 4;
      flags_wait(f3 + y*32, 32, t);                 // h(t) ready (K3 of step t-1)
      if (p.dl[y*64] >= t)
        gemm_phase<8,2>(p, smem, y*64, x*64, t);
      flag_store(&f1[y*16 + x], t + 1);
    }
    if (t == 255) break;
    // phase 2: attention on all 256 blocks
    {
      const int y = b >> 6;
      if (t < p.dl[b]){
        flags_wait(f1 + y*16, 4, t + 1);            // dec_att tiles (x 0..3)
        attn_phase(p, smem, b, t, f1 + y*16 + 4, t + 1);  // gatev tiles waited inside
      }
      flag_store(&f2[b], t + 1);
    }
    // phase 3: K3 GEMM + LSTM on blocks 0..127 (32 x-tiles x 4 y-groups)
    if (b < 128){
      const int x = b & 31, y = b >> 5;
      flags_wait(f2 + y*64, 64, t + 1);             // z rows ready
      if (p.dl[y*64] > t)
        gemm_phase<20,3>(p, smem, y*64, x*64, t);
      flag_store(&f3[y*32 + x], t + 1);
    }
  }
}

extern "C" void kernel_launch(void* const* d_in, const int* in_sizes, int n_in,
                              void* d_out, int out_size, void* d_ws, size_t ws_size,
                              hipStream_t stream){
  (void)in_sizes; (void)n_in; (void)out_size; (void)ws_size;
  const float* enc   = (const float*)d_in[0];
  const int*   caps  = (const int*)d_in[1];
  const int*   clens = (const int*)d_in[2];
  const float* Wenc  = (const float*)d_in[3];
  const float* benc  = (const float*)d_in[4];
  const float* Wdec  = (const float*)d_in[5];
  const float* bdec  = (const float*)d_in[6];
  const float* Wfull = (const float*)d_in[7];
  const float* bfull = (const float*)d_in[8];
  const float* emb   = (const float*)d_in[9];
  const float* Wfc   = (const float*)d_in[10];
  const float* bfc   = (const float*)d_in[11];
  const float* Wih   = (const float*)d_in[12];
  const float* bih   = (const float*)d_in[13];
  const float* Whh   = (const float*)d_in[14];
  const float* bhh   = (const float*)d_in[15];
  const float* Winh  = (const float*)d_in[16];
  const float* binh  = (const float*)d_in[17];
  const float* Winc  = (const float*)d_in[18];
  const float* binc  = (const float*)d_in[19];
  const float* Wfb   = (const float*)d_in[20];
  const float* bfb   = (const float*)d_in[21];

  float* out       = (float*)d_out;
  float* out_preds = out;                  // 256*255*193
  float* out_caps  = out + 12599040;       // 256*256
  float* out_dl    = out + 12664576;       // 256
  float* out_alph  = out + 12664832;       // 256*255*196
  float* out_si    = out + 25459712;       // 256

  char* w = (char*)d_ws;
  size_t off = 0;
  auto alloc = [&](size_t bytes) -> void* {
    void* pp = w + off; off += (bytes + 255) & ~(size_t)255; return pp;
  };
  int*   si      = (int*)  alloc(256*4);
  int*   dlw     = (int*)  alloc(256*4);
  int*   caps_s  = (int*)  alloc(65536*4);
  float* c       = (float*)alloc(131072*4);
  float* dec_att = (float*)alloc(65536*4);
  float* gatev   = (float*)alloc(131072*4);
  float* bc0     = (float*)alloc(1024*4);
  float* bc1     = (float*)alloc(1024*4);
  float* bc3     = (float*)alloc(2048*4);
  int*   ctr     = (int*)  alloc(1024*4);
  u16*   mean_bf = (u16*)  alloc(131072*2);
  u16*   h_bf    = (u16*)  alloc(131072*2);
  u16*   z_bf    = (u16*)  alloc(327680*2);
  u16*   Wc0     = (u16*)  alloc(524288*2);
  u16*   Wc1     = (u16*)  alloc(524288*2);
  u16*   Wc3     = (u16*)  alloc(2621440*2);
  u16*   Wenc_bf = (u16*)  alloc(131072*2);
  u16*   emb_bf  = (u16*)  alloc(49408*2);
  u16*   enc_sb  = (u16*)  alloc(25690112ull*2);   // 256 x 196 x 512 bf16
  u16*   enc_att = (u16*)  alloc(12845056ull*2);   // 50176 x 256 bf16

  k_zero<<<1024, 256, 0, stream>>>(out_preds, 12599040/4, out_alph, 12794880/4, ctr);
  k_sort<<<1, 256, 0, stream>>>(clens, si, dlw, out_dl, out_si);
  k_caps<<<256, 256, 0, stream>>>(caps, si, caps_s, out_caps);
  k_prep<<<256, 256, 0, stream>>>(enc, si, enc_sb);
  k_mean<<<256, 256, 0, stream>>>(enc, si, mean_bf);
  ConcatP cp{Wdec,bdec,Wfb,bfb,Wfc,bfc,Wih,bih,Whh,bhh,Winh,binh,Winc,binc,Wenc,emb,
             Wc0,Wc1,Wc3,Wenc_bf,emb_bf,bc0,bc1,bc3};
  k_concat<<<2048, 256, 0, stream>>>(cp);

  { // h0 / c0 : M=256, N=1024, K=512
    MfmaP g{};
    g.A = mean_bf; g.Bw = Wc0; g.bias = bc0; g.K = 512; g.N = 1024;
    g.h_bf = h_bf; g.c = c;
    k_mfma<1,1><<<dim3(16,4), 256, 0, stream>>>(g);
  }
  { // enc_att : M=50176, N=256, K=512, bf16 out
    MfmaP g{};
    g.A = enc_sb; g.Bw = Wenc_bf; g.bias = benc; g.K = 512; g.N = 256;
    g.out_bf = enc_att;
    k_mfma<0,2><<<dim3(2,784), 256, 0, stream>>>(g);
  }

  PersistP pp{};
  pp.Wc1 = Wc1; pp.bc1 = bc1; pp.Wc3 = Wc3; pp.bc3 = bc3;
  pp.h_bf = h_bf; pp.c = c; pp.z_bf = z_bf;
  pp.dec_att = dec_att; pp.gatev = gatev; pp.preds = out_preds; pp.alphas = out_alph;
  pp.enc_att = enc_att; pp.enc_sb = enc_sb;
  pp.wfull = Wfull; pp.bfull = bfull;
  pp.emb_bf = emb_bf; pp.caps_s = caps_s;
  pp.dl = dlw; pp.ctr = ctr;

  const int shmem = 98304;   // > 160KB/2: forces 1 block/CU, guaranteed spread
  hipFuncSetAttribute((const void*)k_persist,
                      hipFuncAttributeMaxDynamicSharedMemorySize, shmem);

  void* kargs[] = { (void*)&pp };
  hipError_t e = hipLaunchCooperativeKernel((const void*)k_persist, dim3(256), dim3(1024),
                                            kargs, shmem, stream);
  if (e != hipSuccess){
    // fallback: plain launch (256 blocks x 1024 threads, 1 block/CU by LDS)
    k_persist<<<dim3(256), dim3(1024), shmem, stream>>>(pp);
  }
}

// Round 7
// 7556.369 us; speedup vs baseline: 1.4391x; 1.4391x over previous
//
#include <hip/hip_runtime.h>
#include <cstdint>
#include <cstddef>

// B=256, P=196, C=512, D=512, A=256, E=256, V=193, TC=256, T=255

typedef unsigned short u16;
typedef unsigned int u32;
typedef unsigned long long ull;
typedef __attribute__((ext_vector_type(8))) short short8;
typedef __attribute__((ext_vector_type(4))) float f32x4;

__device__ __forceinline__ float sigf(float x){ return 1.f/(1.f+expf(-x)); }
__device__ __forceinline__ u16 f2bf(float f){
  u32 u = __builtin_bit_cast(u32, f);
  u32 r = (u + 0x7fffu + ((u>>16)&1u)) >> 16;
  return (u16)r;
}
__device__ __forceinline__ float bf2f(u16 u){
  u32 x = ((u32)u) << 16;
  return __builtin_bit_cast(float, x);
}

// ---- coherent (LLC-level) relaxed access for SAME-LAUNCH cross-block data ----
__device__ __forceinline__ void st_dev_f32(float* p, float v){
  __hip_atomic_store(p, v, __ATOMIC_RELAXED, __HIP_MEMORY_SCOPE_AGENT);
}
__device__ __forceinline__ float ld_dev_f32(const float* p){
  return __hip_atomic_load(p, __ATOMIC_RELAXED, __HIP_MEMORY_SCOPE_AGENT);
}
__device__ __forceinline__ void st_dev_u16(u16* p, u16 v){
  __hip_atomic_store(p, v, __ATOMIC_RELAXED, __HIP_MEMORY_SCOPE_AGENT);
}
__device__ __forceinline__ void st_dev_u32(u32* p, u32 v){
  __hip_atomic_store(p, v, __ATOMIC_RELAXED, __HIP_MEMORY_SCOPE_AGENT);
}
__device__ __forceinline__ ull ld_dev_u64(const ull* p){
  return __hip_atomic_load(p, __ATOMIC_RELAXED, __HIP_MEMORY_SCOPE_AGENT);
}

// ---- flag-based sync (R5-verified): producer stores to its own slot after
// __syncthreads (drains the block's coherent stores); consumer polls wave-parallel. ----
__device__ __forceinline__ void flag_store(int* f, int v){
  __syncthreads();
  if (threadIdx.x == 0)
    __hip_atomic_store(f, v, __ATOMIC_RELAXED, __HIP_MEMORY_SCOPE_AGENT);
}
__device__ __forceinline__ void flags_wait(const int* f, int n, int target){
  if (threadIdx.x < 64){
    const int lane = threadIdx.x;
    int spins = 0;
    for (;;){
      int v = (lane < n) ? __hip_atomic_load(&f[lane], __ATOMIC_RELAXED, __HIP_MEMORY_SCOPE_AGENT)
                         : 0x7fffffff;
      if (__all(v >= target)) break;
      if (++spins > (1<<20)) break;   // bailout: wrong results, never a hang
      __builtin_amdgcn_s_sleep(1);
    }
  }
  __syncthreads();
}

// ---------------- zero preds/alphas + sync flags ----------------
__global__ void k_zero(float* a, int na4, float* b, int nb4, int* ctr){
  int i = blockIdx.x*blockDim.x + threadIdx.x;
  int stride = gridDim.x*blockDim.x;
  float4 z = make_float4(0.f,0.f,0.f,0.f);
  for (int j = i; j < na4; j += stride) ((float4*)a)[j] = z;
  for (int j = i; j < nb4; j += stride) ((float4*)b)[j] = z;
  if (i < 512) ctr[i] = 0;
}

// ---------------- sort (stable descending by length) ----------------
__global__ void k_sort(const int* cap_lens, int* si, int* dlw, float* out_dl, float* out_si){
  __shared__ int lens[256];
  int tid = threadIdx.x;
  lens[tid] = cap_lens[tid];
  __syncthreads();
  int L = lens[tid];
  int rank = 0;
  for (int j = 0; j < 256; ++j){
    int Lj = lens[j];
    rank += ((Lj > L) || (Lj == L && j < tid)) ? 1 : 0;
  }
  si[rank] = tid;
  dlw[rank] = L - 1;
  out_dl[rank] = (float)(L - 1);
  out_si[rank] = (float)tid;
}

// ---------------- caps gather ----------------
__global__ void k_caps(const int* caps, const int* si, int* caps_s, float* out_caps){
  int b = blockIdx.x, t = threadIdx.x;
  int v = caps[si[b]*256 + t];
  caps_s[b*256 + t] = v;
  out_caps[b*256 + t] = (float)v;
}

// ---------------- gather+convert encoder rows to bf16 (sorted order) ----------------
__global__ void k_prep(const float* enc, const int* si, u16* enc_sb){
  int b = blockIdx.x, tid = threadIdx.x;
  const float* src = enc + (size_t)si[b]*100352;   // 196*512
  u16* dst = enc_sb + (size_t)b*100352;
  for (int i = tid; i < 25088; i += 256){
    float4 v = *(const float4*)&src[i*4];
    ushort4 o;
    o.x = f2bf(v.x); o.y = f2bf(v.y); o.z = f2bf(v.z); o.w = f2bf(v.w);
    *(ushort4*)&dst[i*4] = o;
  }
}

// ---------------- mean of encoder rows (sorted order), bf16 out ----------------
__global__ void k_mean(const float* enc, const int* si, u16* mean_bf){
  int b = blockIdx.x, tid = threadIdx.x;
  const float* eb = enc + (size_t)si[b]*100352;
  int cc = 2*tid;
  float s0 = 0.f, s1 = 0.f;
  #pragma unroll 4
  for (int pp = 0; pp < 196; ++pp){
    float2 v = *(const float2*)&eb[(size_t)pp*512 + cc];
    s0 += v.x; s1 += v.y;
  }
  mean_bf[b*512 + cc]     = f2bf(s0 * (1.f/196.f));
  mean_bf[b*512 + cc + 1] = f2bf(s1 * (1.f/196.f));
}

// ---------------- weight concat + bf16 convert ----------------
struct ConcatP {
  const float *Wdec,*bdec,*Wfb,*bfb,*Wfc,*bfc,*Wih,*bih,*Whh,*bhh,*Winh,*binh,*Winc,*binc,*Wenc,*emb;
  u16 *Wc0,*Wc1,*Wc3,*Wenc_bf,*emb_bf;
  float *bc0,*bc1,*bc3;
};
__global__ void k_concat(ConcatP p){
  int idx = blockIdx.x*blockDim.x + threadIdx.x;
  int stride = gridDim.x*blockDim.x;
  for (int i = idx; i < 1024*512; i += stride){
    int n = i >> 9, k = i & 511;
    float v = (n < 512) ? p.Winh[n*512 + k] : p.Winc[(n-512)*512 + k];
    p.Wc0[i] = f2bf(v);
  }
  for (int i = idx; i < 1024; i += stride)
    p.bc0[i] = (i < 512) ? p.binh[i] : p.binc[i-512];
  for (int i = idx; i < 1024*512; i += stride){
    int n = i >> 9, k = i & 511;
    float v = (n < 256) ? p.Wdec[n*512+k]
            : (n < 768) ? p.Wfb[(n-256)*512+k]
            : (n < 961) ? p.Wfc[(n-768)*512+k] : 0.f;
    p.Wc1[i] = f2bf(v);
  }
  for (int i = idx; i < 1024; i += stride)
    p.bc1[i] = (i < 256) ? p.bdec[i] : (i < 768) ? p.bfb[i-256] : (i < 961) ? p.bfc[i-768] : 0.f;
  // Wc3: gate-interleaved [W_ih | W_hh] (2048 x 1280), row n'=4*j+g -> orig row g*512+j
  for (int i = idx; i < 2048*1280; i += stride){
    int n = i / 1280, k = i - n*1280;
    int j = n >> 2, g = n & 3, orow = g*512 + j;
    float v = (k < 768) ? p.Wih[orow*768 + k] : p.Whh[orow*512 + (k - 768)];
    p.Wc3[i] = f2bf(v);
  }
  for (int i = idx; i < 2048; i += stride){
    int j = i >> 2, g = i & 3, orow = g*512 + j;
    p.bc3[i] = p.bih[orow] + p.bhh[orow];
  }
  for (int i = idx; i < 256*512; i += stride) p.Wenc_bf[i] = f2bf(p.Wenc[i]);
  for (int i = idx; i < 193*256; i += stride) p.emb_bf[i] = f2bf(p.emb[i]);
}

// ---------------- bf16 MFMA GEMM (register-staged, 4 waves) — prologue only ----------------
// MODE 0: enc_att -> bf16 (+bias);  MODE 1: init h/c
struct MfmaP {
  const u16* A; const u16* Bw; const float* bias;
  int K, N;
  u16* out_bf;
  u16* h_bf; float* c;
};

template<int MODE, int NT>
__global__ __launch_bounds__(256) void k_mfma(MfmaP p){
  __shared__ __align__(16) unsigned char smem[16384 + 16384*NT];
  u16* As0 = (u16*)smem;                 // [2][64*64]
  u16* Bs0 = (u16*)(smem + 16384);       // [2][64*64*NT]

  const int tid  = threadIdx.x;
  const int bn0  = blockIdx.x * 64 * NT;
  const int bm0  = blockIdx.y * 64;
  const int wave = tid >> 6;
  const int lane = tid & 63;
  const int ln   = lane & 15;
  const int quad = lane >> 4;

  f32x4 acc[4][NT] = {};
  short8 pa[2], pb[2*NT];

  const int srow = tid >> 3;          // 0..31
  const int sgc  = tid & 7;           // granule col 0..7

  #pragma unroll
  for (int r = 0; r < 2; ++r)
    pa[r] = *(const short8*)(p.A + (size_t)(bm0 + srow + 32*r)*p.K + sgc*8);
  #pragma unroll
  for (int r = 0; r < 2*NT; ++r)
    pb[r] = *(const short8*)(p.Bw + (size_t)(bn0 + srow + 32*r)*p.K + sgc*8);
  #pragma unroll
  for (int r = 0; r < 2; ++r){
    int row = srow + 32*r;
    *(short8*)&As0[row*64 + ((sgc ^ (row & 7))<<3)] = pa[r];
  }
  #pragma unroll
  for (int r = 0; r < 2*NT; ++r){
    int row = srow + 32*r;
    *(short8*)&Bs0[row*64 + ((sgc ^ (row & 7))<<3)] = pb[r];
  }

  const int nIter = p.K >> 6;
  int ib = 0;
  for (int it = 0; ; ){
    __syncthreads();
    const bool more = (it + 1 < nIter);
    if (more){
      int k0 = (it + 1) << 6;
      #pragma unroll
      for (int r = 0; r < 2; ++r)
        pa[r] = *(const short8*)(p.A + (size_t)(bm0 + srow + 32*r)*p.K + k0 + sgc*8);
      #pragma unroll
      for (int r = 0; r < 2*NT; ++r)
        pb[r] = *(const short8*)(p.Bw + (size_t)(bn0 + srow + 32*r)*p.K + k0 + sgc*8);
    }
    const u16* As = &As0[ib*4096];
    const u16* Bs = &Bs0[ib*4096*NT];
    #pragma unroll
    for (int kk = 0; kk < 2; ++kk){
      short8 af[4], bfr[NT];
      #pragma unroll
      for (int mt = 0; mt < 4; ++mt){
        int row = mt*16 + ln;
        int g = kk*4 + quad;
        af[mt] = *(const short8*)&As[row*64 + ((g ^ (row & 7))<<3)];
      }
      #pragma unroll
      for (int nt = 0; nt < NT; ++nt){
        int row = (wave*NT + nt)*16 + ln;
        int g = kk*4 + quad;
        bfr[nt] = *(const short8*)&Bs[row*64 + ((g ^ (row & 7))<<3)];
      }
      #pragma unroll
      for (int mt = 0; mt < 4; ++mt)
        #pragma unroll
        for (int nt = 0; nt < NT; ++nt)
          acc[mt][nt] = __builtin_amdgcn_mfma_f32_16x16x32_bf16(af[mt], bfr[nt], acc[mt][nt], 0, 0, 0);
    }
    if (!more) break;
    ib ^= 1;
    u16* Aw = &As0[ib*4096];
    u16* Bww = &Bs0[ib*4096*NT];
    #pragma unroll
    for (int r = 0; r < 2; ++r){
      int row = srow + 32*r;
      *(short8*)&Aw[row*64 + ((sgc ^ (row & 7))<<3)] = pa[r];
    }
    #pragma unroll
    for (int r = 0; r < 2*NT; ++r){
      int row = srow + 32*r;
      *(short8*)&Bww[row*64 + ((sgc ^ (row & 7))<<3)] = pb[r];
    }
    ++it;
  }

  #pragma unroll
  for (int nt = 0; nt < NT; ++nt){
    int n = bn0 + (wave*NT + nt)*16 + ln;
    float bv = p.bias[n];
    #pragma unroll
    for (int mt = 0; mt < 4; ++mt)
      #pragma unroll
      for (int r = 0; r < 4; ++r){
        int m = bm0 + mt*16 + quad*4 + r;
        float v = acc[mt][nt][r] + bv;
        if (MODE == 0){
          p.out_bf[(size_t)m*p.N + n] = f2bf(v);
        } else { // MODE 1
          if (n < 512) p.h_bf[m*512 + n] = f2bf(v);
          else         p.c[m*512 + n - 512] = v;
        }
      }
  }
}

// ---------------- per-step fused kernel: K1 + attn + K3 in one dispatch ----------------
struct StepP {
  const u16* Wc1; const float* bc1;
  const u16* Wc3; const float* bc3;
  u16* h_bf; float* c; u16* z_bf;
  float* dec_att; float* gatev; float* preds; float* alphas;
  const u16* enc_att; const u16* enc_sb;
  const float* wfull; const float* bfull;
  const u16* emb_bf; const int* caps_s;
  const int* dl;
  int* ctr;   // f1[4][16] at +0, f2[256] at +64
  int t;
};

// reg-staged ring GEMM over 64x64 tile, 16 waves, K-chunks of 64 (R4/R5-verified).
// COH: A loaded via LLC-coherent relaxed atomics (same-launch producer);
// otherwise normal cached loads (previous-launch data, kernel-boundary visible).
template<int NC, int MODE, bool COH>
__device__ void gemm_phase(const StepP& p, unsigned char* smem, int bm0, int bn0, int t){
  constexpr int K = NC * 64;
  constexpr int DP = (NC < 4) ? NC : 4;
  const u16* A    = (MODE == 2) ? p.h_bf : p.z_bf;
  const u16* Bw   = (MODE == 2) ? p.Wc1  : p.Wc3;
  const float* bias = (MODE == 2) ? p.bc1 : p.bc3;

  const int tid = threadIdx.x;
  const int w = tid >> 6, l = tid & 63;
  const int half = tid >> 9;              // 0: stage A, 1: stage B
  const int loc = tid & 511;
  const int r = loc >> 3, g = loc & 7;    // row 0..63, granule 0..7
  u16* lds0 = (u16*)smem;                 // slot: A [64][64] u16, B at +4096; slot stride 8192 u16
  u16* ldst = lds0 + (half ? 4096 : 0) + r*64 + ((g ^ (r & 7)) << 3);
  const u16* gp = half ? (Bw + (size_t)(bn0 + r)*K + g*8)
                       : (A  + (size_t)(bm0 + r)*K + g*8);
  const int mt = w >> 2, nt = w & 3;
  const int ln = l & 15, quad = l >> 4;
  f32x4 acc = {0.f,0.f,0.f,0.f};

  ull buf[DP][2];
  auto issue = [&](int ci, int slot){
    const u16* q = gp + ci*64;
    if (COH && half == 0){
      buf[slot][0] = ld_dev_u64((const ull*)q);
      buf[slot][1] = ld_dev_u64((const ull*)q + 1);
    } else {
      buf[slot][0] = ((const ull*)q)[0];
      buf[slot][1] = ((const ull*)q)[1];
    }
  };
  auto wr = [&](int ci, int slot){
    u16* d = ldst + (ci & 1)*8192;
    ((ull*)d)[0] = buf[slot][0];
    ((ull*)d)[1] = buf[slot][1];
  };
  auto compute = [&](int ci){
    const u16* As = lds0 + (ci & 1)*8192;
    const u16* Bs = As + 4096;
    #pragma unroll
    for (int kk = 0; kk < 2; ++kk){
      int gg = kk*4 + quad;
      int ra = mt*16 + ln;
      short8 af = *(const short8*)&As[ra*64 + ((gg ^ (ra & 7))<<3)];
      int rb = nt*16 + ln;
      short8 bv = *(const short8*)&Bs[rb*64 + ((gg ^ (rb & 7))<<3)];
      acc = __builtin_amdgcn_mfma_f32_16x16x32_bf16(af, bv, acc, 0, 0, 0);
    }
  };

  #pragma unroll
  for (int s = 0; s < DP; ++s) issue(s, s);
  wr(0, 0);
  asm volatile("s_waitcnt lgkmcnt(0)" ::: "memory");
  __builtin_amdgcn_s_barrier();
  #pragma unroll
  for (int ci = 0; ci < NC; ++ci){
    if (ci + 1 < NC) wr(ci + 1, (ci + 1) % DP);
    if (ci + DP < NC) issue(ci + DP, (ci + DP) % DP);
    compute(ci);
    asm volatile("s_waitcnt lgkmcnt(0)" ::: "memory");
    __builtin_amdgcn_s_barrier();
  }

  if (MODE == 2){
    const int n = bn0 + nt*16 + ln;
    const float bv = bias[n];
    #pragma unroll
    for (int rr = 0; rr < 4; ++rr){
      int m = bm0 + mt*16 + quad*4 + rr;
      float v = acc[rr] + bv;
      if (n < 256)      st_dev_f32(&p.dec_att[m*256 + n], v);
      else if (n < 768) st_dev_f32(&p.gatev[m*512 + n - 256], sigf(v));
      else if (n < 961){
        int tp = t - 1;
        if (tp >= 0)
          p.preds[((size_t)m*255 + tp)*193 + (n - 768)] = (tp < p.dl[m]) ? v : 0.f;
      }
    }
  } else {
    // MODE 3: regroup gates via LDS, fused LSTM pointwise.
    // h/c consumed next launch (kernel boundary) -> normal cached stores.
    float* Cs = (float*)smem;           // 64 x 68 f32 overlay
    const int n_loc = nt*16 + ln;
    const float bv = bias[bn0 + n_loc];
    #pragma unroll
    for (int rr = 0; rr < 4; ++rr)
      Cs[(mt*16 + quad*4 + rr)*68 + n_loc] = acc[rr] + bv;
    __syncthreads();
    {
      int m = tid >> 4, jl = tid & 15;   // 64 rows x 16 quads = 1024
      float4 g4 = *(const float4*)&Cs[m*68 + jl*4];
      int gm = bm0 + m;
      int gj = (bn0 >> 2) + jl;
      if (t < p.dl[gm]){
        float ig = sigf(g4.x), fg = sigf(g4.y);
        float gg = tanhf(g4.z), og = sigf(g4.w);
        float cn = fg * p.c[gm*512 + gj] + ig * gg;   // c block-private across launches
        float hn = og * tanhf(cn);
        p.c[gm*512 + gj] = cn;
        p.h_bf[gm*512 + gj] = f2bf(hn);
      }
    }
  }
}

// attention body for 1024 threads (R5-verified); gatev wait deferred to z-assembly.
__device__ void attn_phase(const StepP& p, unsigned char* smem_raw, int b, int t,
                           const int* f_gate, int target){
  float* da  = (float*)smem_raw;        // 256
  float* wfs = da + 256;                // 256
  float* sc  = wfs + 256;               // 256
  float* awe = sc + 256;                // 4 x 512
  float* red = awe + 2048;              // 32
  const int tid = threadIdx.x;
  if (tid < 256){
    da[tid]  = ld_dev_f32(&p.dec_att[b*256 + tid]);
    wfs[tid] = p.wfull[tid];
  }
  __syncthreads();

  // scores: thread (pr, aq) partial over 64 A-entries
  {
    const int pr = tid >> 2, aq = tid & 3;
    float s = 0.f;
    if (pr < 196){
      const u16* row = p.enc_att + ((size_t)b*196 + pr)*256 + aq*64;
      const float* dd = &da[aq*64];
      const float* ww = &wfs[aq*64];
      #pragma unroll
      for (int i = 0; i < 8; ++i){
        short8 v = *(const short8*)(row + i*8);
        #pragma unroll
        for (int j = 0; j < 8; ++j)
          s += fmaxf(bf2f((u16)v[j]) + dd[i*8+j], 0.f) * ww[i*8+j];
      }
    }
    s += __shfl_xor(s, 1, 64);
    s += __shfl_xor(s, 2, 64);
    if ((tid & 3) == 0 && pr < 196) sc[pr] = s + p.bfull[0];
  }
  __syncthreads();

  const int wid = tid >> 6, lane = tid & 63;
  float sv = (tid < 196) ? sc[tid] : -1e30f;
  float mx = sv;
  for (int o = 32; o > 0; o >>= 1) mx = fmaxf(mx, __shfl_down(mx, o, 64));
  if (lane == 0) red[wid] = mx;
  __syncthreads();
  if (tid == 0) red[16] = fmaxf(fmaxf(red[0], red[1]), fmaxf(red[2], red[3]));
  __syncthreads();
  mx = red[16];
  float e = (tid < 196) ? expf(sv - mx) : 0.f;
  float sm = e;
  for (int o = 32; o > 0; o >>= 1) sm += __shfl_down(sm, o, 64);
  if (lane == 0) red[wid] = sm;
  __syncthreads();
  if (tid == 0) red[16] = red[0] + red[1] + red[2] + red[3];
  __syncthreads();
  const float inv = 1.f / red[16];
  if (tid < 256) sc[tid] = e * inv;
  __syncthreads();
  if (tid < 196)
    p.alphas[((size_t)b*255 + t)*196 + tid] = sc[tid];

  // awe: thread (q, cp)
  {
    const int q = tid >> 8, cp = tid & 255, cc = 2*cp;
    const u16* eb = p.enc_sb + (size_t)b*100352;
    const int p0 = q*49;
    float v0 = 0.f, v1 = 0.f;
    #pragma unroll 7
    for (int i = 0; i < 49; ++i){
      int pp = p0 + i;
      u32 u = *(const u32*)&eb[(size_t)pp*512 + cc];
      float a = sc[pp];
      v0 += a * bf2f((u16)(u & 0xffffu));
      v1 += a * bf2f((u16)(u >> 16));
    }
    *(float2*)&awe[q*512 + cc] = make_float2(v0, v1);
  }

  // gatev tiles ready? (also serves as the pre-combine barrier)
  flags_wait(f_gate, 8, target);

  if (tid < 256){
    const int cc = 2*tid;
    float v0 = awe[0*512+cc]   + awe[1*512+cc]   + awe[2*512+cc]   + awe[3*512+cc];
    float v1 = awe[0*512+cc+1] + awe[1*512+cc+1] + awe[2*512+cc+1] + awe[3*512+cc+1];
    u16* zb = p.z_bf + (size_t)b*1280;
    float g0 = ld_dev_f32(&p.gatev[b*512 + cc]);
    float g1 = ld_dev_f32(&p.gatev[b*512 + cc + 1]);
    st_dev_u16(&zb[256 + cc],     f2bf(g0 * v0));
    st_dev_u16(&zb[256 + cc + 1], f2bf(g1 * v1));
    int tok = p.caps_s[b*256 + t];
    st_dev_u16(&zb[tid], p.emb_bf[tok*256 + tid]);
    // h(t) written by PREVIOUS launch's K3 -> normal load is fresh
    st_dev_u32((u32*)&zb[768 + cc], *(const u32*)&p.h_bf[b*512 + cc]);
  }
}

// one dispatch per step: blocks 0..63 K1, 64..319 attn, 320..447 K3.
// K3(t-1) -> K1(t) boundary comes free from stream ordering.
__global__ __launch_bounds__(1024) void k_step(StepP p){
  __shared__ __align__(16) unsigned char smem[40960];
  const int b = blockIdx.x;
  const int t = p.t;
  int* f1 = p.ctr;          // [4][16] K1 tile flags
  int* f2 = p.ctr + 64;     // [256]   attn flags
  if (b < 64){
    // K1: dec_att + gate + preds(t-1): M=256, N=1024(pad of 961), K=512
    const int x = b & 15, y = b >> 4;
    if (p.dl[y*64] >= t)
      gemm_phase<8,2,false>(p, smem, y*64, x*64, t);
    flag_store(&f1[y*16 + x], t + 1);
  } else if (b < 320){
    // attention for batch element bb
    const int bb = b - 64;
    const int y = bb >> 6;
    if (t < p.dl[bb]){
      flags_wait(f1 + y*16, 4, t + 1);                   // dec_att tiles (x 0..3)
      attn_phase(p, smem, bb, t, f1 + y*16 + 4, t + 1);  // gatev tiles (x 4..11) inside
    }
    flag_store(&f2[bb], t + 1);
  } else {
    // K3: gates GEMM + fused LSTM: M=256, N=2048, K=1280
    const int idx = b - 320, x = idx & 31, y = idx >> 5;
    if (p.dl[y*64] > t){
      flags_wait(f2 + y*64, 64, t + 1);                  // z rows ready
      gemm_phase<20,3,true>(p, smem, y*64, x*64, t);
    }
  }
}

extern "C" void kernel_launch(void* const* d_in, const int* in_sizes, int n_in,
                              void* d_out, int out_size, void* d_ws, size_t ws_size,
                              hipStream_t stream){
  (void)in_sizes; (void)n_in; (void)out_size; (void)ws_size;
  const float* enc   = (const float*)d_in[0];
  const int*   caps  = (const int*)d_in[1];
  const int*   clens = (const int*)d_in[2];
  const float* Wenc  = (const float*)d_in[3];
  const float* benc  = (const float*)d_in[4];
  const float* Wdec  = (const float*)d_in[5];
  const float* bdec  = (const float*)d_in[6];
  const float* Wfull = (const float*)d_in[7];
  const float* bfull = (const float*)d_in[8];
  const float* emb   = (const float*)d_in[9];
  const float* Wfc   = (const float*)d_in[10];
  const float* bfc   = (const float*)d_in[11];
  const float* Wih   = (const float*)d_in[12];
  const float* bih   = (const float*)d_in[13];
  const float* Whh   = (const float*)d_in[14];
  const float* bhh   = (const float*)d_in[15];
  const float* Winh  = (const float*)d_in[16];
  const float* binh  = (const float*)d_in[17];
  const float* Winc  = (const float*)d_in[18];
  const float* binc  = (const float*)d_in[19];
  const float* Wfb   = (const float*)d_in[20];
  const float* bfb   = (const float*)d_in[21];

  float* out       = (float*)d_out;
  float* out_preds = out;                  // 256*255*193
  float* out_caps  = out + 12599040;       // 256*256
  float* out_dl    = out + 12664576;       // 256
  float* out_alph  = out + 12664832;       // 256*255*196
  float* out_si    = out + 25459712;       // 256

  char* w = (char*)d_ws;
  size_t off = 0;
  auto alloc = [&](size_t bytes) -> void* {
    void* pp = w + off; off += (bytes + 255) & ~(size_t)255; return pp;
  };
  int*   si      = (int*)  alloc(256*4);
  int*   dlw     = (int*)  alloc(256*4);
  int*   caps_s  = (int*)  alloc(65536*4);
  float* c       = (float*)alloc(131072*4);
  float* dec_att = (float*)alloc(65536*4);
  float* gatev   = (float*)alloc(131072*4);
  float* bc0     = (float*)alloc(1024*4);
  float* bc1     = (float*)alloc(1024*4);
  float* bc3     = (float*)alloc(2048*4);
  int*   ctr     = (int*)  alloc(1024*4);
  u16*   mean_bf = (u16*)  alloc(131072*2);
  u16*   h_bf    = (u16*)  alloc(131072*2);
  u16*   z_bf    = (u16*)  alloc(327680*2);
  u16*   Wc0     = (u16*)  alloc(524288*2);
  u16*   Wc1     = (u16*)  alloc(524288*2);
  u16*   Wc3     = (u16*)  alloc(2621440*2);
  u16*   Wenc_bf = (u16*)  alloc(131072*2);
  u16*   emb_bf  = (u16*)  alloc(49408*2);
  u16*   enc_sb  = (u16*)  alloc(25690112ull*2);   // 256 x 196 x 512 bf16
  u16*   enc_att = (u16*)  alloc(12845056ull*2);   // 50176 x 256 bf16

  k_zero<<<1024, 256, 0, stream>>>(out_preds, 12599040/4, out_alph, 12794880/4, ctr);
  k_sort<<<1, 256, 0, stream>>>(clens, si, dlw, out_dl, out_si);
  k_caps<<<256, 256, 0, stream>>>(caps, si, caps_s, out_caps);
  k_prep<<<256, 256, 0, stream>>>(enc, si, enc_sb);
  k_mean<<<256, 256, 0, stream>>>(enc, si, mean_bf);
  ConcatP cp{Wdec,bdec,Wfb,bfb,Wfc,bfc,Wih,bih,Whh,bhh,Winh,binh,Winc,binc,Wenc,emb,
             Wc0,Wc1,Wc3,Wenc_bf,emb_bf,bc0,bc1,bc3};
  k_concat<<<2048, 256, 0, stream>>>(cp);

  { // h0 / c0 : M=256, N=1024, K=512
    MfmaP g{};
    g.A = mean_bf; g.Bw = Wc0; g.bias = bc0; g.K = 512; g.N = 1024;
    g.h_bf = h_bf; g.c = c;
    k_mfma<1,1><<<dim3(16,4), 256, 0, stream>>>(g);
  }
  { // enc_att : M=50176, N=256, K=512, bf16 out
    MfmaP g{};
    g.A = enc_sb; g.Bw = Wenc_bf; g.bias = benc; g.K = 512; g.N = 256;
    g.out_bf = enc_att;
    k_mfma<0,2><<<dim3(2,784), 256, 0, stream>>>(g);
  }

  StepP sp{};
  sp.Wc1 = Wc1; sp.bc1 = bc1; sp.Wc3 = Wc3; sp.bc3 = bc3;
  sp.h_bf = h_bf; sp.c = c; sp.z_bf = z_bf;
  sp.dec_att = dec_att; sp.gatev = gatev; sp.preds = out_preds; sp.alphas = out_alph;
  sp.enc_att = enc_att; sp.enc_sb = enc_sb;
  sp.wfull = Wfull; sp.bfull = bfull;
  sp.emb_bf = emb_bf; sp.caps_s = caps_s;
  sp.dl = dlw; sp.ctr = ctr;

  for (int t = 0; t <= 255; ++t){
    sp.t = t;
    k_step<<<448, 1024, 0, stream>>>(sp);
  }
}